// Round 5
// baseline (171.267 us; speedup 1.0000x reference)
//
#include <hip/hip_runtime.h>

// Problem constants (from reference): B=16, C=1, H=1024, W=1024, fp32.
#define HH 1024
#define WW 1024
#define BAND 16          // rows per block, processed as TWO 8-row burst phases
#define NT 256

// ext_vector type so __builtin_nontemporal_load accepts it.
typedef __attribute__((ext_vector_type(4))) float f32x4;

__device__ __forceinline__ float fmax3(float a, float b, float c) {
    return fmaxf(a, fmaxf(b, c));
}

__device__ __forceinline__ float loss_elem(float x, float t, float dil) {
    // target/dilated are exactly binary {0,1}: weight = 1 + 4*dil + 15*t
    float w = fmaf(15.0f, t, fmaf(4.0f, dil, 1.0f));
    // BCE with logits: max(x,0) - x*t + log1p(exp(-|x|))
    float a  = fabsf(x);
    float sp = __logf(1.0f + __expf(-a));
    return w * (fmaxf(x, 0.0f) - x * t + sp);
}

// R14: two-phase burst, BAND=16, nt loads.
//   Model (R12 verified): nt reads stream pure-HBM at ~3.75 TB/s, MSHR-capped
//   -> issued bytes are the only lever. BAND=16 cuts target halo 25%->12.5%
//   (151 -> 142.6 MB issued) but R13 proved a single 34-load burst spills
//   (WRITE_SIZE 36MB, VGPR=64). Fix: two 8-row burst phases:
//     A: load target rows -1..8 (t0..t9) + pred 0..7 (x0..x7), compute rows 0-7
//     sched_barrier(0)   // pin: stops the scheduler re-merging the bursts
//     B: load target rows 9..16 (n0..n7) + pred 8..15 (y0..y7), reuse t8,t9,
//        compute rows 8-15
//   Peak live ~95 VGPR per phase -> fits the launch_bounds(256,4) 128-VGPR
//   budget. Each phase is still a deep burst (R10/R11: paced issue loses 2x).
//   Decision: WRITE_SIZE(main) in MBs or VGPR=64 => spilled again => revert R12.
template <bool PER_WAVE>
__global__ __launch_bounds__(NT, 4) void dilatedweightBCE_main(
        const float* __restrict__ pred,
        const float* __restrict__ target,
        float* __restrict__ partial) {
    __shared__ float swave[NT / 64];

    const int t    = threadIdx.x;
    const int lane = t & 63;
    const int wv   = t >> 6;
    const int c    = t * 4;                  // column strip (NT*4 == WW)

    // --- XCD-contiguous swizzle: l -> (img, h0) ---
    const int l    = blockIdx.x;             // [0, 1024)
    const int xcd  = l & 7;
    const int j    = l >> 3;                 // [0, 128)
    const int img  = j >> 3;                 // [0, 16)
    const int slab = j & 7;                  // [0, 8)
    const int h0   = (xcd * 8 + slab) * BAND;    // XCD x owns rows [128x,128x+128)

    const float* timg = target + (size_t)img * HH * WW;
    const float* pimg = pred   + (size_t)img * HH * WW;
    const float* tp   = timg + (size_t)h0 * WW + c;
    const float* pp   = pimg + (size_t)h0 * WW + c;

    const bool top = (h0 > 0);
    const bool bot = (h0 + BAND < HH);
    const f32x4 zero = (f32x4)(0.0f);

    // halo column (c-1 for lane0, c+4 for lane63) — 2 active lanes/wave
    const bool hval = (lane == 0) ? (c > 0) : ((lane == 63) ? (c + 4 < WW) : false);
    const float* thp = timg + (size_t)h0 * WW + ((lane == 0) ? (c - 1) : (c + 4));

    #define NTL4(p) __builtin_nontemporal_load((const f32x4*)(p))
    #define NTL1(p) __builtin_nontemporal_load(p)

    float s = 0.0f;

    // One row: a,m,d = target rows r-1,r,r+1; ha,hb,hc = halo col same rows;
    // xx = pred row r. All names, no arrays.
    #define ROW(ta,tm,td, ha,hb,hc, xx) {                                        \
        float vmx = fmax3((ta).x, (tm).x, (td).x);                               \
        float vmy = fmax3((ta).y, (tm).y, (td).y);                               \
        float vmz = fmax3((ta).z, (tm).z, (td).z);                               \
        float vmw = fmax3((ta).w, (tm).w, (td).w);                               \
        float hmax = fmax3(ha, hb, hc);                                          \
        float lft = __shfl_up(vmw, 1);                                           \
        float rgt = __shfl_down(vmx, 1);                                         \
        if (lane == 0)  lft = hmax;                                              \
        if (lane == 63) rgt = hmax;                                              \
        s += loss_elem((xx).x, (tm).x, fmax3(lft, vmx, vmy));                    \
        s += loss_elem((xx).y, (tm).y, fmax3(vmx, vmy, vmz));                    \
        s += loss_elem((xx).z, (tm).z, fmax3(vmy, vmz, vmw));                    \
        s += loss_elem((xx).w, (tm).w, fmax3(vmz, vmw, rgt));                    \
    }

    // ================= Phase A: rows 0..7 =================
    // t0..t9 = target rows h0-1 .. h0+8 (rows 0..8 always in-image since
    // h0+8 <= 1016); x0..x7 = pred rows h0..h0+7.
    f32x4 t0 = top ? NTL4(tp - WW) : zero;
    f32x4 t1 = NTL4(tp);
    f32x4 t2 = NTL4(tp + 1 * WW);
    f32x4 t3 = NTL4(tp + 2 * WW);
    f32x4 t4 = NTL4(tp + 3 * WW);
    f32x4 t5 = NTL4(tp + 4 * WW);
    f32x4 t6 = NTL4(tp + 5 * WW);
    f32x4 t7 = NTL4(tp + 6 * WW);
    f32x4 t8 = NTL4(tp + 7 * WW);
    f32x4 t9 = NTL4(tp + 8 * WW);
    f32x4 x0 = NTL4(pp);
    f32x4 x1 = NTL4(pp + 1 * WW);
    f32x4 x2 = NTL4(pp + 2 * WW);
    f32x4 x3 = NTL4(pp + 3 * WW);
    f32x4 x4 = NTL4(pp + 4 * WW);
    f32x4 x5 = NTL4(pp + 5 * WW);
    f32x4 x6 = NTL4(pp + 6 * WW);
    f32x4 x7 = NTL4(pp + 7 * WW);

    float hv0 = (hval && top) ? NTL1(thp - WW) : 0.0f;
    float hv1 = hval ? NTL1(thp)          : 0.0f;
    float hv2 = hval ? NTL1(thp + 1 * WW) : 0.0f;
    float hv3 = hval ? NTL1(thp + 2 * WW) : 0.0f;
    float hv4 = hval ? NTL1(thp + 3 * WW) : 0.0f;
    float hv5 = hval ? NTL1(thp + 4 * WW) : 0.0f;
    float hv6 = hval ? NTL1(thp + 5 * WW) : 0.0f;
    float hv7 = hval ? NTL1(thp + 6 * WW) : 0.0f;
    float hv8 = hval ? NTL1(thp + 7 * WW) : 0.0f;
    float hv9 = hval ? NTL1(thp + 8 * WW) : 0.0f;

    ROW(t0, t1, t2, hv0, hv1, hv2, x0)
    ROW(t1, t2, t3, hv1, hv2, hv3, x1)
    ROW(t2, t3, t4, hv2, hv3, hv4, x2)
    ROW(t3, t4, t5, hv3, hv4, hv5, x3)
    ROW(t4, t5, t6, hv4, hv5, hv6, x4)
    ROW(t5, t6, t7, hv5, hv6, hv7, x5)
    ROW(t6, t7, t8, hv6, hv7, hv8, x6)
    ROW(t7, t8, t9, hv7, hv8, hv9, x7)

    // Pin: phase-B loads must not be hoisted up into phase A (R13's spill).
    __builtin_amdgcn_sched_barrier(0);

    // ================= Phase B: rows 8..15 =================
    // Carry t8 (row 7), t9 (row 8), hv8, hv9. New: target rows 9..16,
    // pred rows 8..15. Row 16 exists iff bot.
    f32x4 n0 = NTL4(tp +  9 * WW);
    f32x4 n1 = NTL4(tp + 10 * WW);
    f32x4 n2 = NTL4(tp + 11 * WW);
    f32x4 n3 = NTL4(tp + 12 * WW);
    f32x4 n4 = NTL4(tp + 13 * WW);
    f32x4 n5 = NTL4(tp + 14 * WW);
    f32x4 n6 = NTL4(tp + 15 * WW);
    f32x4 n7 = bot ? NTL4(tp + 16 * WW) : zero;
    f32x4 y0 = NTL4(pp +  8 * WW);
    f32x4 y1 = NTL4(pp +  9 * WW);
    f32x4 y2 = NTL4(pp + 10 * WW);
    f32x4 y3 = NTL4(pp + 11 * WW);
    f32x4 y4 = NTL4(pp + 12 * WW);
    f32x4 y5 = NTL4(pp + 13 * WW);
    f32x4 y6 = NTL4(pp + 14 * WW);
    f32x4 y7 = NTL4(pp + 15 * WW);

    float g0 = hval ? NTL1(thp +  9 * WW) : 0.0f;
    float g1 = hval ? NTL1(thp + 10 * WW) : 0.0f;
    float g2 = hval ? NTL1(thp + 11 * WW) : 0.0f;
    float g3 = hval ? NTL1(thp + 12 * WW) : 0.0f;
    float g4 = hval ? NTL1(thp + 13 * WW) : 0.0f;
    float g5 = hval ? NTL1(thp + 14 * WW) : 0.0f;
    float g6 = hval ? NTL1(thp + 15 * WW) : 0.0f;
    float g7 = (hval && bot) ? NTL1(thp + 16 * WW) : 0.0f;

    ROW(t8, t9, n0, hv8, hv9, g0, y0)
    ROW(t9, n0, n1, hv9, g0,  g1, y1)
    ROW(n0, n1, n2, g0,  g1,  g2, y2)
    ROW(n1, n2, n3, g1,  g2,  g3, y3)
    ROW(n2, n3, n4, g2,  g3,  g4, y4)
    ROW(n3, n4, n5, g3,  g4,  g5, y5)
    ROW(n4, n5, n6, g4,  g5,  g6, y6)
    ROW(n5, n6, n7, g5,  g6,  g7, y7)

    #undef ROW
    #undef NTL4
    #undef NTL1

    // ---- wave reduction ----
    #pragma unroll
    for (int off = 32; off > 0; off >>= 1)
        s += __shfl_down(s, off);

    if (PER_WAVE) {
        if (lane == 0)
            partial[(size_t)l * (NT / 64) + wv] = s;   // no barrier, no LDS
    } else {
        if (lane == 0) swave[wv] = s;
        __syncthreads();
        if (t == 0) {
            float tot = 0.0f;
            #pragma unroll
            for (int i = 0; i < NT / 64; ++i) tot += swave[i];
            partial[l] = tot;
        }
    }
}

__global__ __launch_bounds__(1024) void dilatedweightBCE_reduce(
        const float* __restrict__ partial,
        float* __restrict__ out,
        int npart4,            // number of float4 chunks
        float inv_n) {
    __shared__ float swave[16];
    const int t = threadIdx.x;

    float s = 0.0f;
    const float4* p4 = (const float4*)partial;
    for (int i = t; i < npart4; i += 1024) {
        float4 v = p4[i];
        s += v.x + v.y + v.z + v.w;
    }

    #pragma unroll
    for (int off = 32; off > 0; off >>= 1)
        s += __shfl_down(s, off);

    const int lane = t & 63;
    if (lane == 0) swave[t >> 6] = s;
    __syncthreads();
    if (t == 0) {
        float tot = 0.0f;
        #pragma unroll
        for (int i = 0; i < 16; ++i) tot += swave[i];
        out[0] = tot * inv_n;
    }
}

extern "C" void kernel_launch(void* const* d_in, const int* in_sizes, int n_in,
                              void* d_out, int out_size, void* d_ws, size_t ws_size,
                              hipStream_t stream) {
    const float* pred   = (const float*)d_in[0];
    const float* target = (const float*)d_in[1];
    float* out     = (float*)d_out;
    float* partial = (float*)d_ws;

    const int n  = in_sizes[0];              // B*C*H*W
    const int Bn = n / (HH * WW);            // batch (16)
    const int nblocks = (HH / BAND) * Bn;    // 1024

    const size_t need = (size_t)nblocks * (NT / 64) * sizeof(float);  // 16 KB
    if (ws_size >= need) {
        dilatedweightBCE_main<true><<<nblocks, NT, 0, stream>>>(pred, target, partial);
        dilatedweightBCE_reduce<<<1, 1024, 0, stream>>>(partial, out,
                                                        nblocks * (NT / 64) / 4,
                                                        1.0f / (float)n);
    } else {
        dilatedweightBCE_main<false><<<nblocks, NT, 0, stream>>>(pred, target, partial);
        dilatedweightBCE_reduce<<<1, 1024, 0, stream>>>(partial, out,
                                                        nblocks / 4,
                                                        1.0f / (float)n);
    }
}

// Round 6
// 143.980 us; speedup vs baseline: 1.1895x; 1.1895x over previous
//
#include <hip/hip_runtime.h>

// Problem constants (from reference): B=16, C=1, H=1024, W=1024, fp32.
#define HH 1024
#define WW 1024
#define BAND 16          // rows per block; thread = 16 rows x float4 strip
#define NT 256

// ext_vector type so __builtin_nontemporal_load accepts it.
typedef __attribute__((ext_vector_type(4))) float f32x4;

__device__ __forceinline__ float fmax3(float a, float b, float c) {
    return fmaxf(a, fmaxf(b, c));
}

__device__ __forceinline__ float loss_elem(float x, float t, float dil) {
    // target/dilated are exactly binary {0,1}: weight = 1 + 4*dil + 15*t
    float w = fmaf(15.0f, t, fmaf(4.0f, dil, 1.0f));
    // BCE with logits: max(x,0) - x*t + log1p(exp(-|x|))
    float a  = fabsf(x);
    float sp = __logf(1.0f + __expf(-a));
    return w * (fmaxf(x, 0.0f) - x * t + sp);
}

// R15: single-burst BAND=16 + PINNED occupancy (amdgpu_waves_per_eu(2,2)).
//   Diagnosis of R10/R11/R13/R14: launch_bounds(256,4) sets waves/EU in
//   [4,8]; the AMDGPU scheduler targets the MAX (8 waves -> 64 VGPR) and
//   the allocator then SPILLS instead of relaxing occupancy. Every kernel
//   needing >64 live regs got VGPR=64 + MBs of WRITE_SIZE (36-90MB).
//   Fix: waves_per_eu(2,2) pins 2 waves/EU -> hard 256-VGPR budget; the
//   34-load burst (~170 live regs) fits without spill.
//   Model (R12): nt reads are service-rate-saturated ~3.75 TB/s; in-flight
//   needed is only ~5.5KB/CU so 8 waves/CU occupancy is ample. Bytes are
//   the only lever: BAND=16 => 18 target rows per 16 output rows (12.5%
//   halo vs 25%) = 151 -> 142.6 MB issued.
//   Decision: VGPR=64 again => attribute ignored => revert R12/roofline.
//             main >= 40us, no spill => bytes don't bind => R12 roofline.
//             main ~ 37-38us => byte model confirmed.
template <bool PER_WAVE>
__global__ __launch_bounds__(NT)
__attribute__((amdgpu_waves_per_eu(2, 2)))
void dilatedweightBCE_main(
        const float* __restrict__ pred,
        const float* __restrict__ target,
        float* __restrict__ partial) {
    __shared__ float swave[NT / 64];

    const int t    = threadIdx.x;
    const int lane = t & 63;
    const int wv   = t >> 6;
    const int c    = t * 4;                  // column strip (NT*4 == WW)

    // --- XCD-contiguous swizzle: l -> (img, h0) ---
    const int l    = blockIdx.x;             // [0, 1024)
    const int xcd  = l & 7;
    const int j    = l >> 3;                 // [0, 128)
    const int img  = j >> 3;                 // [0, 16)
    const int slab = j & 7;                  // [0, 8)
    const int h0   = (xcd * 8 + slab) * BAND;    // XCD x owns rows [128x,128x+128)

    const float* timg = target + (size_t)img * HH * WW;
    const float* pimg = pred   + (size_t)img * HH * WW;
    const f32x4 zero = (f32x4)(0.0f);

    // ---- ALL 34 independent loads issued before any use (nontemporal) ----
    f32x4 tr[BAND + 2];                     // target rows h0-1 .. h0+BAND
    tr[0] = (h0 > 0)
          ? __builtin_nontemporal_load((const f32x4*)(timg + (size_t)(h0 - 1) * WW + c))
          : zero;
    #pragma unroll
    for (int r = 0; r < BAND; ++r)
        tr[r + 1] = __builtin_nontemporal_load(
            (const f32x4*)(timg + (size_t)(h0 + r) * WW + c));
    tr[BAND + 1] = (h0 + BAND < HH)
          ? __builtin_nontemporal_load((const f32x4*)(timg + (size_t)(h0 + BAND) * WW + c))
          : zero;

    f32x4 xr[BAND];                         // pred rows h0 .. h0+BAND-1
    #pragma unroll
    for (int r = 0; r < BAND; ++r)
        xr[r] = __builtin_nontemporal_load(
            (const f32x4*)(pimg + (size_t)(h0 + r) * WW + c));

    // ---- halo column for wave-boundary lanes (nt too: never allocate) ----
    float halo[BAND];
    #pragma unroll
    for (int r = 0; r < BAND; ++r) halo[r] = 0.0f;
    if (lane == 0 || lane == 63) {
        const int pc = (lane == 0) ? c - 1 : c + 4;
        if (pc >= 0 && pc < WW) {
            float hv[BAND + 2];
            hv[0] = (h0 > 0)
                  ? __builtin_nontemporal_load(timg + (size_t)(h0 - 1) * WW + pc) : 0.0f;
            #pragma unroll
            for (int r = 0; r < BAND; ++r)
                hv[r + 1] = __builtin_nontemporal_load(timg + (size_t)(h0 + r) * WW + pc);
            hv[BAND + 1] = (h0 + BAND < HH)
                  ? __builtin_nontemporal_load(timg + (size_t)(h0 + BAND) * WW + pc) : 0.0f;
            #pragma unroll
            for (int r = 0; r < BAND; ++r)
                halo[r] = fmax3(hv[r], hv[r + 1], hv[r + 2]);
        }
    }

    // ---- dilation + loss, row by row (row j needs only tr[j..j+2]) ----
    float s = 0.0f;
    #pragma unroll
    for (int r = 0; r < BAND; ++r) {
        f32x4 a = tr[r], m = tr[r + 1], d = tr[r + 2];
        float vmx = fmax3(a.x, m.x, d.x);
        float vmy = fmax3(a.y, m.y, d.y);
        float vmz = fmax3(a.z, m.z, d.z);
        float vmw = fmax3(a.w, m.w, d.w);

        float lft = __shfl_up(vmw, 1);
        float rgt = __shfl_down(vmx, 1);
        if (lane == 0)  lft = halo[r];
        if (lane == 63) rgt = halo[r];

        float d0 = fmax3(lft, vmx, vmy);
        float d1 = fmax3(vmx, vmy, vmz);
        float d2 = fmax3(vmy, vmz, vmw);
        float d3 = fmax3(vmz, vmw, rgt);

        f32x4 x = xr[r];
        s += loss_elem(x.x, m.x, d0);
        s += loss_elem(x.y, m.y, d1);
        s += loss_elem(x.z, m.z, d2);
        s += loss_elem(x.w, m.w, d3);
    }

    // ---- wave reduction ----
    #pragma unroll
    for (int off = 32; off > 0; off >>= 1)
        s += __shfl_down(s, off);

    if (PER_WAVE) {
        if (lane == 0)
            partial[(size_t)l * (NT / 64) + wv] = s;   // no barrier, no LDS
    } else {
        if (lane == 0) swave[wv] = s;
        __syncthreads();
        if (t == 0) {
            float tot = 0.0f;
            #pragma unroll
            for (int i = 0; i < NT / 64; ++i) tot += swave[i];
            partial[l] = tot;
        }
    }
}

__global__ __launch_bounds__(1024) void dilatedweightBCE_reduce(
        const float* __restrict__ partial,
        float* __restrict__ out,
        int npart4,            // number of float4 chunks
        float inv_n) {
    __shared__ float swave[16];
    const int t = threadIdx.x;

    float s = 0.0f;
    const float4* p4 = (const float4*)partial;
    for (int i = t; i < npart4; i += 1024) {
        float4 v = p4[i];
        s += v.x + v.y + v.z + v.w;
    }

    #pragma unroll
    for (int off = 32; off > 0; off >>= 1)
        s += __shfl_down(s, off);

    const int lane = t & 63;
    if (lane == 0) swave[t >> 6] = s;
    __syncthreads();
    if (t == 0) {
        float tot = 0.0f;
        #pragma unroll
        for (int i = 0; i < 16; ++i) tot += swave[i];
        out[0] = tot * inv_n;
    }
}

extern "C" void kernel_launch(void* const* d_in, const int* in_sizes, int n_in,
                              void* d_out, int out_size, void* d_ws, size_t ws_size,
                              hipStream_t stream) {
    const float* pred   = (const float*)d_in[0];
    const float* target = (const float*)d_in[1];
    float* out     = (float*)d_out;
    float* partial = (float*)d_ws;

    const int n  = in_sizes[0];              // B*C*H*W
    const int Bn = n / (HH * WW);            // batch (16)
    const int nblocks = (HH / BAND) * Bn;    // 1024

    const size_t need = (size_t)nblocks * (NT / 64) * sizeof(float);  // 16 KB
    if (ws_size >= need) {
        dilatedweightBCE_main<true><<<nblocks, NT, 0, stream>>>(pred, target, partial);
        dilatedweightBCE_reduce<<<1, 1024, 0, stream>>>(partial, out,
                                                        nblocks * (NT / 64) / 4,
                                                        1.0f / (float)n);
    } else {
        dilatedweightBCE_main<false><<<nblocks, NT, 0, stream>>>(pred, target, partial);
        dilatedweightBCE_reduce<<<1, 1024, 0, stream>>>(partial, out,
                                                        nblocks / 4,
                                                        1.0f / (float)n);
    }
}

// Round 7
// 140.204 us; speedup vs baseline: 1.2216x; 1.0269x over previous
//
#include <hip/hip_runtime.h>

// Problem constants (from reference): B=16, C=1, H=1024, W=1024, fp32.
#define HH 1024
#define WW 1024
#define BAND 16          // rows per block; thread = 16 rows x float4 strip
#define NT 256

// ext_vector type so __builtin_nontemporal_load accepts it.
typedef __attribute__((ext_vector_type(4))) float f32x4;

__device__ __forceinline__ float fmax3(float a, float b, float c) {
    return fmaxf(a, fmaxf(b, c));
}

__device__ __forceinline__ float loss_elem(float x, float t, float dil) {
    // target/dilated are exactly binary {0,1}: weight = 1 + 4*dil + 15*t
    float w = fmaf(15.0f, t, fmaf(4.0f, dil, 1.0f));
    // BCE with logits: max(x,0) - x*t + log1p(exp(-|x|))
    float a  = fabsf(x);
    float sp = __logf(1.0f + __expf(-a));
    return w * (fmaxf(x, 0.0f) - x * t + sp);
}

// R16: R15 (BAND=16 single nt burst, waves_per_eu(2,2) -> no spill,
//   main <40.2us, total 143.98) + LDS wave-boundary exchange replacing the
//   column-halo loads.
//   Model (confirmed R12/R15): nt reads stream pure-HBM at ~3.8 TB/s flat;
//   issued bytes are the only lever. The 2-lanes/wave scalar halo loads
//   (2 x 18 x 4096 waves x 64B lines, ~9.4MB) are redundant: the block
//   spans the full row, so lane0(wave w) needs exactly vm.w of
//   lane63(wave w-1) — an intra-block value. Exchange via 512B LDS:
//   boundary lanes precompute their column's 3-row max for all 16 rows,
//   one __syncthreads, row loop reads the neighbor's value. Image-edge
//   columns use 0 (= reduce_window -inf pad on binary targets).
//   Decision: main ~35.5-36.5 => byte model again; main unchanged =>
//   halo scalars were MSHR-merged (free) => bytes at minimum => roofline.
template <bool PER_WAVE>
__global__ __launch_bounds__(NT)
__attribute__((amdgpu_waves_per_eu(2, 2)))
void dilatedweightBCE_main(
        const float* __restrict__ pred,
        const float* __restrict__ target,
        float* __restrict__ partial) {
    __shared__ float swave[NT / 64];
    __shared__ float ldsL[NT / 64][BAND];   // vm.x of lane0 of each wave
    __shared__ float ldsR[NT / 64][BAND];   // vm.w of lane63 of each wave

    const int t    = threadIdx.x;
    const int lane = t & 63;
    const int wv   = t >> 6;
    const int c    = t * 4;                  // column strip (NT*4 == WW)

    // --- XCD-contiguous swizzle: l -> (img, h0) ---
    const int l    = blockIdx.x;             // [0, 1024)
    const int xcd  = l & 7;
    const int j    = l >> 3;                 // [0, 128)
    const int img  = j >> 3;                 // [0, 16)
    const int slab = j & 7;                  // [0, 8)
    const int h0   = (xcd * 8 + slab) * BAND;    // XCD x owns rows [128x,128x+128)

    const float* timg = target + (size_t)img * HH * WW;
    const float* pimg = pred   + (size_t)img * HH * WW;
    const f32x4 zero = (f32x4)(0.0f);

    // ---- ALL 34 independent loads issued before any use (nontemporal) ----
    f32x4 tr[BAND + 2];                     // target rows h0-1 .. h0+BAND
    tr[0] = (h0 > 0)
          ? __builtin_nontemporal_load((const f32x4*)(timg + (size_t)(h0 - 1) * WW + c))
          : zero;
    #pragma unroll
    for (int r = 0; r < BAND; ++r)
        tr[r + 1] = __builtin_nontemporal_load(
            (const f32x4*)(timg + (size_t)(h0 + r) * WW + c));
    tr[BAND + 1] = (h0 + BAND < HH)
          ? __builtin_nontemporal_load((const f32x4*)(timg + (size_t)(h0 + BAND) * WW + c))
          : zero;

    f32x4 xr[BAND];                         // pred rows h0 .. h0+BAND-1
    #pragma unroll
    for (int r = 0; r < BAND; ++r)
        xr[r] = __builtin_nontemporal_load(
            (const f32x4*)(pimg + (size_t)(h0 + r) * WW + c));

    // ---- wave-boundary column exchange via LDS (replaces halo loads) ----
    // lane0's left neighbor column (c-1) is lane63 of wave wv-1; lane63's
    // right neighbor (c+4) is lane0 of wave wv+1. Boundary lanes publish
    // their own column's 3-row vertical max for every row.
    if (lane == 0) {
        #pragma unroll
        for (int r = 0; r < BAND; ++r)
            ldsL[wv][r] = fmax3(tr[r].x, tr[r + 1].x, tr[r + 2].x);
    }
    if (lane == 63) {
        #pragma unroll
        for (int r = 0; r < BAND; ++r)
            ldsR[wv][r] = fmax3(tr[r].w, tr[r + 1].w, tr[r + 2].w);
    }
    __syncthreads();

    // ---- dilation + loss, row by row (row j needs only tr[j..j+2]) ----
    float s = 0.0f;
    #pragma unroll
    for (int r = 0; r < BAND; ++r) {
        f32x4 a = tr[r], m = tr[r + 1], d = tr[r + 2];
        float vmx = fmax3(a.x, m.x, d.x);
        float vmy = fmax3(a.y, m.y, d.y);
        float vmz = fmax3(a.z, m.z, d.z);
        float vmw = fmax3(a.w, m.w, d.w);

        float lft = __shfl_up(vmw, 1);
        float rgt = __shfl_down(vmx, 1);
        if (lane == 0)  lft = (wv > 0)            ? ldsR[wv - 1][r] : 0.0f;
        if (lane == 63) rgt = (wv < NT / 64 - 1)  ? ldsL[wv + 1][r] : 0.0f;

        float d0 = fmax3(lft, vmx, vmy);
        float d1 = fmax3(vmx, vmy, vmz);
        float d2 = fmax3(vmy, vmz, vmw);
        float d3 = fmax3(vmz, vmw, rgt);

        f32x4 x = xr[r];
        s += loss_elem(x.x, m.x, d0);
        s += loss_elem(x.y, m.y, d1);
        s += loss_elem(x.z, m.z, d2);
        s += loss_elem(x.w, m.w, d3);
    }

    // ---- wave reduction ----
    #pragma unroll
    for (int off = 32; off > 0; off >>= 1)
        s += __shfl_down(s, off);

    if (PER_WAVE) {
        if (lane == 0)
            partial[(size_t)l * (NT / 64) + wv] = s;   // no extra barrier
    } else {
        if (lane == 0) swave[wv] = s;
        __syncthreads();
        if (t == 0) {
            float tot = 0.0f;
            #pragma unroll
            for (int i = 0; i < NT / 64; ++i) tot += swave[i];
            partial[l] = tot;
        }
    }
}

__global__ __launch_bounds__(1024) void dilatedweightBCE_reduce(
        const float* __restrict__ partial,
        float* __restrict__ out,
        int npart4,            // number of float4 chunks
        float inv_n) {
    __shared__ float swave[16];
    const int t = threadIdx.x;

    float s = 0.0f;
    const float4* p4 = (const float4*)partial;
    for (int i = t; i < npart4; i += 1024) {
        float4 v = p4[i];
        s += v.x + v.y + v.z + v.w;
    }

    #pragma unroll
    for (int off = 32; off > 0; off >>= 1)
        s += __shfl_down(s, off);

    const int lane = t & 63;
    if (lane == 0) swave[t >> 6] = s;
    __syncthreads();
    if (t == 0) {
        float tot = 0.0f;
        #pragma unroll
        for (int i = 0; i < 16; ++i) tot += swave[i];
        out[0] = tot * inv_n;
    }
}

extern "C" void kernel_launch(void* const* d_in, const int* in_sizes, int n_in,
                              void* d_out, int out_size, void* d_ws, size_t ws_size,
                              hipStream_t stream) {
    const float* pred   = (const float*)d_in[0];
    const float* target = (const float*)d_in[1];
    float* out     = (float*)d_out;
    float* partial = (float*)d_ws;

    const int n  = in_sizes[0];              // B*C*H*W
    const int Bn = n / (HH * WW);            // batch (16)
    const int nblocks = (HH / BAND) * Bn;    // 1024

    const size_t need = (size_t)nblocks * (NT / 64) * sizeof(float);  // 16 KB
    if (ws_size >= need) {
        dilatedweightBCE_main<true><<<nblocks, NT, 0, stream>>>(pred, target, partial);
        dilatedweightBCE_reduce<<<1, 1024, 0, stream>>>(partial, out,
                                                        nblocks * (NT / 64) / 4,
                                                        1.0f / (float)n);
    } else {
        dilatedweightBCE_main<false><<<nblocks, NT, 0, stream>>>(pred, target, partial);
        dilatedweightBCE_reduce<<<1, 1024, 0, stream>>>(partial, out,
                                                        nblocks / 4,
                                                        1.0f / (float)n);
    }
}